// Round 6
// baseline (281.498 us; speedup 1.0000x reference)
//
#include <hip/hip_runtime.h>
#include <hip/hip_bf16.h>
#include <cstdint>

#define NEGV (-10000.0f)

typedef short bf16x8 __attribute__((ext_vector_type(8)));
typedef short bf16x4 __attribute__((ext_vector_type(4)));
typedef float f32x4 __attribute__((ext_vector_type(4)));

__device__ __forceinline__ short f2bf(float f) {
  union { float f; uint32_t u; } v; v.f = f;
  uint32_t u = v.u + 0x7fffu + ((v.u >> 16) & 1u);
  return (short)(u >> 16);
}
__device__ __forceinline__ float b2f(short s) {
  union { uint32_t u; float f; } v; v.u = ((uint32_t)(uint16_t)s) << 16;
  return v.f;
}
__device__ __forceinline__ uint32_t pk2(float lo, float hi) {
  union { __hip_bfloat162 h2; uint32_t u; } cv;
  cv.h2.x = __float2bfloat16(lo);
  cv.h2.y = __float2bfloat16(hi);
  return cv.u;
}

// ---------------- P1: weight combine + bf16 casts ----------------
__global__ void prep_weights(const float* __restrict__ W1, const float* __restrict__ W2,
                             short* __restrict__ Wk, short* __restrict__ Wd,
                             short* __restrict__ W2b) {
  int idx = blockIdx.x * 256 + threadIdx.x;
  if (idx < 32768) {
    int h = idx >> 7, d = idx & 127;
    Wk[idx] = f2bf(W1[h * 512 + 128 + d] - W1[h * 512 + 256 + d]);
  } else if (idx < 65536) {
    int i = idx - 32768;
    int h = i >> 7, d = i & 127;
    Wd[i] = f2bf(W1[h * 512 + 384 + d]);
  } else {
    int i = idx - 65536;
    W2b[i] = f2bf(W2[i]);
  }
}

// ---------------- P2: U[b][h] = b1[h] + sum_d (W1[h][d]+W1[h][256+d]) * q[b][d] ----
__global__ void prep_u(const float* __restrict__ query, const float* __restrict__ W1,
                       const float* __restrict__ b1, float* __restrict__ U) {
  __shared__ float q8[8][128];
  int tid = threadIdx.x;
  int b0 = blockIdx.x * 8;
  for (int i = tid; i < 1024; i += 256)
    q8[i >> 7][i & 127] = query[(size_t)(b0 + (i >> 7)) * 128 + (i & 127)];
  __syncthreads();
  int h = tid;
  const float4* w0 = (const float4*)(W1 + (size_t)h * 512);
  const float4* w1 = (const float4*)(W1 + (size_t)h * 512 + 256);
  float acc[8];
  float bb = b1[h];
#pragma unroll
  for (int i = 0; i < 8; ++i) acc[i] = bb;
  for (int d4 = 0; d4 < 32; ++d4) {
    float4 wa = w0[d4], wb = w1[d4];
    float wv0 = wa.x + wb.x, wv1 = wa.y + wb.y, wv2 = wa.z + wb.z, wv3 = wa.w + wb.w;
#pragma unroll
    for (int i = 0; i < 8; ++i) {
      float4 qv = ((const float4*)q8[i])[d4];
      acc[i] += wv0 * qv.x + wv1 * qv.y + wv2 * qv.z + wv3 * qv.w;
    }
  }
#pragma unroll
  for (int i = 0; i < 8; ++i) U[(size_t)(b0 + i) * 256 + h] = acc[i];
}

// ---------------- K2: scores. Block = (b, l-half of 100), 4 waves. ----------------
// h-split-4 GEMM1 (wave owns 64 h), g-split-4 GEMM2 (wave owns 32 g).
// One barrier per 16-l tile; whole 112-row key tile staged once.
__global__ __launch_bounds__(256) void din_scores(
    const float* __restrict__ query, const float* __restrict__ keys,
    const float* __restrict__ b2p, const float* __restrict__ a1p,
    const float* __restrict__ a2p, const float* __restrict__ W3,
    const float* __restrict__ U, const short* __restrict__ Wk,
    const short* __restrict__ Wd, const short* __restrict__ W2b,
    float* __restrict__ scores_g) {
  __shared__ short Kp[112 * 128];     // 28 KB, XOR-swizzled rows
  __shared__ short H1[2][16 * 256];   // 16 KB, per-tile h1, XOR-swizzled
  __shared__ float wred[4][112];      // per-wave score partials
  __shared__ float Ul[256];
  __shared__ float b2l[128];
  __shared__ float w3l[128];

  const int tid = threadIdx.x;
  const int bq = blockIdx.x;
  const int b = bq >> 1;
  const int lbase = (bq & 1) * 100;
  const int lane = tid & 63, wid = tid >> 6;  // 4 waves
  const int lr = lane & 15, lg = lane >> 4;

  const float a1 = a1p[0], a2 = a2p[0];

  Ul[tid] = U[(size_t)b * 256 + tid];
  if (tid < 128) { b2l[tid] = b2p[tid]; w3l[tid] = W3[tid]; }

  // ---- persistent fragments ----
  // GEMM1 A: M_b[h][d] = Wk + Wd.*q ; wave owns 64 h (nt=0..3)
  bf16x8 mf[4][4];
  {
    const float* qrow = query + (size_t)b * 128;
#pragma unroll
    for (int nt = 0; nt < 4; ++nt) {
      int h = wid * 64 + nt * 16 + lr;
#pragma unroll
      for (int ks = 0; ks < 4; ++ks) {
        int d0 = ks * 32 + lg * 8;
        bf16x8 wk = *(const bf16x8*)(Wk + h * 128 + d0);
        bf16x8 wd = *(const bf16x8*)(Wd + h * 128 + d0);
        float4 q0 = *(const float4*)(qrow + d0);
        float4 q1 = *(const float4*)(qrow + d0 + 4);
        float qv[8] = {q0.x, q0.y, q0.z, q0.w, q1.x, q1.y, q1.z, q1.w};
        float mv[8];
#pragma unroll
        for (int j = 0; j < 8; ++j) mv[j] = b2f(wk[j]) + b2f(wd[j]) * qv[j];
        union { bf16x8 v; uint32_t u[4]; } mm;
#pragma unroll
        for (int j = 0; j < 4; ++j) mm.u[j] = pk2(mv[2 * j], mv[2 * j + 1]);
        mf[nt][ks] = mm.v;
      }
    }
  }
  // GEMM2 A: W2[g][h]; wave owns 32 g (nt2=0..1)
  bf16x8 w2f[2][8];
#pragma unroll
  for (int nt2 = 0; nt2 < 2; ++nt2) {
    int g = wid * 32 + nt2 * 16 + lr;
#pragma unroll
    for (int ks = 0; ks < 8; ++ks)
      w2f[nt2][ks] = *(const bf16x8*)(W2b + g * 256 + ks * 32 + lg * 8);
  }

  // ---- stage 112 key rows (bf16, swizzled); rows >= 100 are zeros ----
  {
    const int rb = tid >> 4;            // 0..15
    const int scol = (tid & 15) * 8;    // 0..120
    for (int pass = 0; pass < 7; ++pass) {
      int srow = pass * 16 + rb;        // 0..111
      float4 s0 = make_float4(0.f, 0.f, 0.f, 0.f), s1 = s0;
      if (srow < 100) {
        const float4* kp4 =
            (const float4*)(keys + ((size_t)b * 200 + lbase + srow) * 128 + scol);
        s0 = kp4[0]; s1 = kp4[1];
      }
      union { bf16x8 v; uint32_t u[4]; } w;
      w.u[0] = pk2(s0.x, s0.y); w.u[1] = pk2(s0.z, s0.w);
      w.u[2] = pk2(s1.x, s1.y); w.u[3] = pk2(s1.z, s1.w);
      *(bf16x8*)(&Kp[srow * 128 + (scol ^ ((srow & 7) << 3))]) = w.v;
    }
  }
  __syncthreads();

  // ---- 7 tiles of 16 l; 1 barrier per tile ----
  for (int t = 0; t < 7; ++t) {
    const int l = t * 16 + lr;
    const int sw = (lr & 7) << 3;       // l&7 == lr&7 (16 | 8)
    // GEMM1: D[h][l]
    bf16x8 kf[4];
#pragma unroll
    for (int ks = 0; ks < 4; ++ks)
      kf[ks] = *(const bf16x8*)(&Kp[l * 128 + ((ks * 32 + lg * 8) ^ sw)]);
    f32x4 acc[4];
#pragma unroll
    for (int nt = 0; nt < 4; ++nt)
#pragma unroll
      for (int r = 0; r < 4; ++r) acc[nt][r] = Ul[wid * 64 + nt * 16 + lg * 4 + r];
#pragma unroll
    for (int ks = 0; ks < 4; ++ks)
#pragma unroll
      for (int nt = 0; nt < 4; ++nt)
        acc[nt] = __builtin_amdgcn_mfma_f32_16x16x32_bf16(mf[nt][ks], kf[ks], acc[nt], 0, 0, 0);
    // PReLU(a1) -> H1[t&1][lr][h], packed 8B writes
    short* h1b = H1[t & 1];
#pragma unroll
    for (int nt = 0; nt < 4; ++nt) {
      float v0 = acc[nt][0], v1 = acc[nt][1], v2 = acc[nt][2], v3 = acc[nt][3];
      v0 = (v0 >= 0.f) ? v0 : a1 * v0;
      v1 = (v1 >= 0.f) ? v1 : a1 * v1;
      v2 = (v2 >= 0.f) ? v2 : a1 * v2;
      v3 = (v3 >= 0.f) ? v3 : a1 * v3;
      union { bf16x4 v; uint32_t u[2]; } hh;
      hh.u[0] = pk2(v0, v1); hh.u[1] = pk2(v2, v3);
      int h0 = wid * 64 + nt * 16 + lg * 4;
      *(bf16x4*)(&h1b[lr * 256 + (h0 ^ sw)]) = hh.v;
    }
    __syncthreads();

    // GEMM2: D[g][l] over full K=256; wave owns 32 g
    f32x4 acc2[2];
#pragma unroll
    for (int nt2 = 0; nt2 < 2; ++nt2)
#pragma unroll
      for (int r = 0; r < 4; ++r) acc2[nt2][r] = b2l[wid * 32 + nt2 * 16 + lg * 4 + r];
#pragma unroll
    for (int ks = 0; ks < 8; ++ks) {
      bf16x8 hf = *(const bf16x8*)(&h1b[lr * 256 + ((ks * 32 + lg * 8) ^ sw)]);
      acc2[0] = __builtin_amdgcn_mfma_f32_16x16x32_bf16(w2f[0][ks], hf, acc2[0], 0, 0, 0);
      acc2[1] = __builtin_amdgcn_mfma_f32_16x16x32_bf16(w2f[1][ks], hf, acc2[1], 0, 0, 0);
    }
    float s = 0.f;
#pragma unroll
    for (int nt2 = 0; nt2 < 2; ++nt2)
#pragma unroll
      for (int r = 0; r < 4; ++r) {
        float v = acc2[nt2][r];
        v = (v >= 0.f) ? v : a2 * v;
        s += v * w3l[wid * 32 + nt2 * 16 + lg * 4 + r];
      }
    s += __shfl_xor(s, 16);
    s += __shfl_xor(s, 32);
    if (lg == 0) wred[wid][t * 16 + lr] = s;
    // no barrier: next tile writes H1[(t+1)&1]; wred slots disjoint per t
  }
  __syncthreads();

  if (tid < 100) {
    float s = wred[0][tid] + wred[1][tid] + wred[2][tid] + wred[3][tid];
    scores_g[(size_t)b * 200 + lbase + tid] = s;
  }
}

// ---------------- K3: masked softmax + weighted sum (streaming) ----------------
__global__ __launch_bounds__(256) void din_wsum(
    const float* __restrict__ keys, const int* __restrict__ mask,
    const float* __restrict__ scores_g, float* __restrict__ out) {
  __shared__ float wl[208];
  __shared__ float red[8];
  __shared__ float opart[8][128];

  const int tid = threadIdx.x;
  const int b = blockIdx.x;
  const int lane = tid & 63, wid = tid >> 6;  // 4 waves

  float val = NEGV;
  int mk = 0;
  if (tid < 200) {
    mk = mask[(size_t)b * 200 + tid];
    val = mk ? scores_g[(size_t)b * 200 + tid] : NEGV;
  }
  float m = val;
#pragma unroll
  for (int off = 1; off < 64; off <<= 1) m = fmaxf(m, __shfl_xor(m, off));
  if (lane == 0) red[wid] = m;
  __syncthreads();
  float smax = fmaxf(fmaxf(red[0], red[1]), fmaxf(red[2], red[3]));
  float pex = (tid < 200 && mk) ? __expf(val - smax) : 0.f;
  float s = pex;
#pragma unroll
  for (int off = 1; off < 64; off <<= 1) s += __shfl_xor(s, off);
  if (lane == 0) red[4 + wid] = s;
  __syncthreads();
  float ssum = red[4] + red[5] + red[6] + red[7];
  float winv = (ssum > 0.f) ? 1.f / ssum : 0.f;
  if (tid < 208) wl[tid] = (tid < 200) ? pex * winv : 0.f;
  __syncthreads();

  {
    const int d4 = (tid & 31) << 2;  // 0..124
    const int slice = tid >> 5;      // 0..7
    float ax = 0.f, ay = 0.f, az = 0.f, aw = 0.f;
    for (int l = slice; l < 200; l += 8) {
      float wv = wl[l];
      float4 kv = *(const float4*)(keys + ((size_t)b * 200 + l) * 128 + d4);
      ax += wv * kv.x; ay += wv * kv.y; az += wv * kv.z; aw += wv * kv.w;
    }
    *(float4*)(&opart[slice][d4]) = make_float4(ax, ay, az, aw);
  }
  __syncthreads();
  if (tid < 128) {
    float acc = 0.f;
#pragma unroll
    for (int i = 0; i < 8; ++i) acc += opart[i][tid];
    out[(size_t)b * 128 + tid] = acc;
  }
}

extern "C" void kernel_launch(void* const* d_in, const int* in_sizes, int n_in,
                              void* d_out, int out_size, void* d_ws, size_t ws_size,
                              hipStream_t stream) {
  const float* query = (const float*)d_in[0];
  const float* keys  = (const float*)d_in[1];
  const int*   maskp = (const int*)d_in[2];
  const float* W1    = (const float*)d_in[3];
  const float* b1    = (const float*)d_in[4];
  const float* a1    = (const float*)d_in[5];
  const float* W2    = (const float*)d_in[6];
  const float* b2    = (const float*)d_in[7];
  const float* a2    = (const float*)d_in[8];
  const float* W3    = (const float*)d_in[9];
  float* out = (float*)d_out;

  // workspace layout
  float* U        = (float*)d_ws;                        // 2 MiB
  short* Wk       = (short*)((char*)d_ws + 2097152);     // 64 KiB
  short* Wd       = Wk + 32768;                          // 64 KiB
  short* W2b      = Wd + 32768;                          // 64 KiB
  float* scores_g = (float*)((char*)d_ws + 2097152 + 196608);  // 1.6 MiB

  prep_weights<<<384, 256, 0, stream>>>(W1, W2, Wk, Wd, W2b);
  prep_u<<<256, 256, 0, stream>>>(query, W1, b1, U);
  din_scores<<<4096, 256, 0, stream>>>(query, keys, b2, a1, a2, W3,
                                       U, Wk, Wd, W2b, scores_g);
  din_wsum<<<2048, 256, 0, stream>>>(keys, maskp, scores_g, out);
}

// Round 7
// 163.980 us; speedup vs baseline: 1.7167x; 1.7167x over previous
//
#include <hip/hip_runtime.h>
#include <hip/hip_bf16.h>
#include <cstdint>

#define NEGV (-10000.0f)

typedef short bf16x8 __attribute__((ext_vector_type(8)));
typedef short bf16x4 __attribute__((ext_vector_type(4)));
typedef float f32x4 __attribute__((ext_vector_type(4)));

__device__ __forceinline__ short f2bf(float f) {
  union { float f; uint32_t u; } v; v.f = f;
  uint32_t u = v.u + 0x7fffu + ((v.u >> 16) & 1u);
  return (short)(u >> 16);
}
__device__ __forceinline__ float b2f(short s) {
  union { uint32_t u; float f; } v; v.u = ((uint32_t)(uint16_t)s) << 16;
  return v.f;
}
__device__ __forceinline__ uint32_t pk2(float lo, float hi) {
  union { __hip_bfloat162 h2; uint32_t u; } cv;
  cv.h2.x = __float2bfloat16(lo);
  cv.h2.y = __float2bfloat16(hi);
  return cv.u;
}

// ---------------- P1: weight combine + bf16 casts ----------------
__global__ void prep_weights(const float* __restrict__ W1, const float* __restrict__ W2,
                             short* __restrict__ Wk, short* __restrict__ Wd,
                             short* __restrict__ W2b) {
  int idx = blockIdx.x * 256 + threadIdx.x;
  if (idx < 32768) {
    int h = idx >> 7, d = idx & 127;
    Wk[idx] = f2bf(W1[h * 512 + 128 + d] - W1[h * 512 + 256 + d]);
  } else if (idx < 65536) {
    int i = idx - 32768;
    int h = i >> 7, d = i & 127;
    Wd[i] = f2bf(W1[h * 512 + 384 + d]);
  } else {
    int i = idx - 65536;
    W2b[i] = f2bf(W2[i]);
  }
}

// ---------------- P2: U[b][h] = b1[h] + sum_d (W1[h][d]+W1[h][256+d]) * q[b][d] ----
__global__ void prep_u(const float* __restrict__ query, const float* __restrict__ W1,
                       const float* __restrict__ b1, float* __restrict__ U) {
  __shared__ float q8[8][128];
  int tid = threadIdx.x;
  int b0 = blockIdx.x * 8;
  for (int i = tid; i < 1024; i += 256)
    q8[i >> 7][i & 127] = query[(size_t)(b0 + (i >> 7)) * 128 + (i & 127)];
  __syncthreads();
  int h = tid;
  const float4* w0 = (const float4*)(W1 + (size_t)h * 512);
  const float4* w1 = (const float4*)(W1 + (size_t)h * 512 + 256);
  float acc[8];
  float bb = b1[h];
#pragma unroll
  for (int i = 0; i < 8; ++i) acc[i] = bb;
  for (int d4 = 0; d4 < 32; ++d4) {
    float4 wa = w0[d4], wb = w1[d4];
    float wv0 = wa.x + wb.x, wv1 = wa.y + wb.y, wv2 = wa.z + wb.z, wv3 = wa.w + wb.w;
#pragma unroll
    for (int i = 0; i < 8; ++i) {
      float4 qv = ((const float4*)q8[i])[d4];
      acc[i] += wv0 * qv.x + wv1 * qv.y + wv2 * qv.z + wv3 * qv.w;
    }
  }
#pragma unroll
  for (int i = 0; i < 8; ++i) U[(size_t)(b0 + i) * 256 + h] = acc[i];
}

// ---------------- K2: scores. Block = b, 4 waves, streaming 16-row tiles ----------
// R7: LDS 29.5KB, 1 barrier/tile, T14 staged loads, T5 setprio, lb(256,2).
__global__ __launch_bounds__(256, 2) void din_scores(
    const float* __restrict__ query, const float* __restrict__ keys,
    const float* __restrict__ b2p, const float* __restrict__ a1p,
    const float* __restrict__ a2p, const float* __restrict__ W3,
    const float* __restrict__ U, const short* __restrict__ Wk,
    const short* __restrict__ Wd, const short* __restrict__ W2b,
    float* __restrict__ scores_g) {
  __shared__ short Kt[2][16 * 128];   // 8 KB: streaming key tiles, XOR-swizzled
  __shared__ short H1[2][16 * 256];   // 16 KB: per-tile h1, XOR-swizzled
  __shared__ float wred[4][208];      // 3.3 KB: per-wave score partials
  __shared__ float Ul[256];
  __shared__ float b2l[128];
  __shared__ float w3l[128];

  const int tid = threadIdx.x;
  const int b = blockIdx.x;
  const int lane = tid & 63, wid = tid >> 6;  // 4 waves
  const int lr = lane & 15, lg = lane >> 4;

  const float a1 = a1p[0], a2 = a2p[0];

  Ul[tid] = U[(size_t)b * 256 + tid];
  if (tid < 128) { b2l[tid] = b2p[tid]; w3l[tid] = W3[tid]; }

  // ---- persistent fragments ----
  // GEMM1 A: M_b[h][d] = Wk + Wd.*q ; wave owns 64 h (nt=0..3)
  bf16x8 mf[4][4];
  {
    const float* qrow = query + (size_t)b * 128;
#pragma unroll
    for (int nt = 0; nt < 4; ++nt) {
      int h = wid * 64 + nt * 16 + lr;
#pragma unroll
      for (int ks = 0; ks < 4; ++ks) {
        int d0 = ks * 32 + lg * 8;
        bf16x8 wk = *(const bf16x8*)(Wk + h * 128 + d0);
        bf16x8 wd = *(const bf16x8*)(Wd + h * 128 + d0);
        float4 q0 = *(const float4*)(qrow + d0);
        float4 q1 = *(const float4*)(qrow + d0 + 4);
        float qv[8] = {q0.x, q0.y, q0.z, q0.w, q1.x, q1.y, q1.z, q1.w};
        float mv[8];
#pragma unroll
        for (int j = 0; j < 8; ++j) mv[j] = b2f(wk[j]) + b2f(wd[j]) * qv[j];
        union { bf16x8 v; uint32_t u[4]; } mm;
#pragma unroll
        for (int j = 0; j < 4; ++j) mm.u[j] = pk2(mv[2 * j], mv[2 * j + 1]);
        mf[nt][ks] = mm.v;
      }
    }
  }
  // GEMM2 A: W2[g][h]; wave owns 32 g (nt2=0..1)
  bf16x8 w2f[2][8];
#pragma unroll
  for (int nt2 = 0; nt2 < 2; ++nt2) {
    int g = wid * 32 + nt2 * 16 + lr;
#pragma unroll
    for (int ks = 0; ks < 8; ++ks)
      w2f[nt2][ks] = *(const bf16x8*)(W2b + g * 256 + ks * 32 + lg * 8);
  }

  // staging geometry: 16 threads/row, 8 floats (32B) per thread
  const int srow = tid >> 4;          // 0..15
  const int scol = (tid & 15) * 8;    // 0..120
  const int ssw = (srow & 7) << 3;

  // prologue: stage tile 0 (rows 0..15, all valid)
  {
    const float4* kp4 = (const float4*)(keys + ((size_t)b * 200 + srow) * 128 + scol);
    float4 s0 = kp4[0], s1 = kp4[1];
    union { bf16x8 v; uint32_t u[4]; } w;
    w.u[0] = pk2(s0.x, s0.y); w.u[1] = pk2(s0.z, s0.w);
    w.u[2] = pk2(s1.x, s1.y); w.u[3] = pk2(s1.z, s1.w);
    *(bf16x8*)(&Kt[0][srow * 128 + (scol ^ ssw)]) = w.v;
  }
  __syncthreads();

  // ---- 13 tiles of 16 l (tile 12: rows 192..199 + 8 zero rows) ----
  for (int t = 0; t < 13; ++t) {
    const int buf = t & 1;

    // T14: issue next-tile global loads now; LDS-write them after GEMM1
    float4 st0, st1;
    if (t < 12) {
      int gl = (t + 1) * 16 + srow;
      st0 = st1 = make_float4(0.f, 0.f, 0.f, 0.f);
      if (gl < 200) {
        const float4* kp4 = (const float4*)(keys + ((size_t)b * 200 + gl) * 128 + scol);
        st0 = kp4[0]; st1 = kp4[1];
      }
    }

    // GEMM1: D[h][l] = M_b · K^T
    const int sw = (lr & 7) << 3;
    bf16x8 kf[4];
#pragma unroll
    for (int ks = 0; ks < 4; ++ks)
      kf[ks] = *(const bf16x8*)(&Kt[buf][lr * 128 + ((ks * 32 + lg * 8) ^ sw)]);
    f32x4 acc[4];
#pragma unroll
    for (int nt = 0; nt < 4; ++nt)
#pragma unroll
      for (int r = 0; r < 4; ++r) acc[nt][r] = Ul[wid * 64 + nt * 16 + lg * 4 + r];
    __builtin_amdgcn_s_setprio(1);
#pragma unroll
    for (int ks = 0; ks < 4; ++ks)
#pragma unroll
      for (int nt = 0; nt < 4; ++nt)
        acc[nt] = __builtin_amdgcn_mfma_f32_16x16x32_bf16(mf[nt][ks], kf[ks], acc[nt], 0, 0, 0);
    __builtin_amdgcn_s_setprio(0);
    // PReLU(a1) -> H1[buf][lr][h], packed 8B writes
    short* h1b = H1[buf];
#pragma unroll
    for (int nt = 0; nt < 4; ++nt) {
      float v0 = acc[nt][0], v1 = acc[nt][1], v2 = acc[nt][2], v3 = acc[nt][3];
      v0 = (v0 >= 0.f) ? v0 : a1 * v0;
      v1 = (v1 >= 0.f) ? v1 : a1 * v1;
      v2 = (v2 >= 0.f) ? v2 : a1 * v2;
      v3 = (v3 >= 0.f) ? v3 : a1 * v3;
      union { bf16x4 v; uint32_t u[2]; } hh;
      hh.u[0] = pk2(v0, v1); hh.u[1] = pk2(v2, v3);
      int h0 = wid * 64 + nt * 16 + lg * 4;
      *(bf16x4*)(&h1b[lr * 256 + (h0 ^ sw)]) = hh.v;
    }

    // write next-tile Kt (other buffer; safe: last readers synced at barrier t-1)
    if (t < 12) {
      union { bf16x8 v; uint32_t u[4]; } w;
      w.u[0] = pk2(st0.x, st0.y); w.u[1] = pk2(st0.z, st0.w);
      w.u[2] = pk2(st1.x, st1.y); w.u[3] = pk2(st1.z, st1.w);
      *(bf16x8*)(&Kt[buf ^ 1][srow * 128 + (scol ^ ssw)]) = w.v;
    }
    __syncthreads();  // the ONLY barrier per tile

    // GEMM2: D[g][l] = W2 · H1^T, K=256
    f32x4 acc2[2];
#pragma unroll
    for (int nt2 = 0; nt2 < 2; ++nt2)
#pragma unroll
      for (int r = 0; r < 4; ++r) acc2[nt2][r] = b2l[wid * 32 + nt2 * 16 + lg * 4 + r];
    __builtin_amdgcn_s_setprio(1);
#pragma unroll
    for (int ks = 0; ks < 8; ++ks) {
      bf16x8 hf = *(const bf16x8*)(&h1b[lr * 256 + ((ks * 32 + lg * 8) ^ sw)]);
      acc2[0] = __builtin_amdgcn_mfma_f32_16x16x32_bf16(w2f[0][ks], hf, acc2[0], 0, 0, 0);
      acc2[1] = __builtin_amdgcn_mfma_f32_16x16x32_bf16(w2f[1][ks], hf, acc2[1], 0, 0, 0);
    }
    __builtin_amdgcn_s_setprio(0);
    float s = 0.f;
#pragma unroll
    for (int nt2 = 0; nt2 < 2; ++nt2)
#pragma unroll
      for (int r = 0; r < 4; ++r) {
        float v = acc2[nt2][r];
        v = (v >= 0.f) ? v : a2 * v;
        s += v * w3l[wid * 32 + nt2 * 16 + lg * 4 + r];
      }
    s += __shfl_xor(s, 16);
    s += __shfl_xor(s, 32);
    if (lg == 0) wred[wid][t * 16 + lr] = s;
    // no barrier here: all tile-(t+1) LDS targets are the other buffers
  }
  __syncthreads();

  if (tid < 200) {
    float s = wred[0][tid] + wred[1][tid] + wred[2][tid] + wred[3][tid];
    scores_g[(size_t)b * 200 + tid] = s;
  }
}

// ---------------- K3: masked softmax + weighted sum (streaming) ----------------
__global__ __launch_bounds__(256) void din_wsum(
    const float* __restrict__ keys, const int* __restrict__ mask,
    const float* __restrict__ scores_g, float* __restrict__ out) {
  __shared__ float wl[208];
  __shared__ float red[8];
  __shared__ float opart[8][128];

  const int tid = threadIdx.x;
  const int b = blockIdx.x;
  const int lane = tid & 63, wid = tid >> 6;  // 4 waves

  float val = NEGV;
  int mk = 0;
  if (tid < 200) {
    mk = mask[(size_t)b * 200 + tid];
    val = mk ? scores_g[(size_t)b * 200 + tid] : NEGV;
  }
  float m = val;
#pragma unroll
  for (int off = 1; off < 64; off <<= 1) m = fmaxf(m, __shfl_xor(m, off));
  if (lane == 0) red[wid] = m;
  __syncthreads();
  float smax = fmaxf(fmaxf(red[0], red[1]), fmaxf(red[2], red[3]));
  float pex = (tid < 200 && mk) ? __expf(val - smax) : 0.f;
  float s = pex;
#pragma unroll
  for (int off = 1; off < 64; off <<= 1) s += __shfl_xor(s, off);
  if (lane == 0) red[4 + wid] = s;
  __syncthreads();
  float ssum = red[4] + red[5] + red[6] + red[7];
  float winv = (ssum > 0.f) ? 1.f / ssum : 0.f;
  if (tid < 208) wl[tid] = (tid < 200) ? pex * winv : 0.f;
  __syncthreads();

  {
    const int d4 = (tid & 31) << 2;  // 0..124
    const int slice = tid >> 5;      // 0..7
    float ax = 0.f, ay = 0.f, az = 0.f, aw = 0.f;
    for (int l = slice; l < 200; l += 8) {
      float wv = wl[l];
      float4 kv = *(const float4*)(keys + ((size_t)b * 200 + l) * 128 + d4);
      ax += wv * kv.x; ay += wv * kv.y; az += wv * kv.z; aw += wv * kv.w;
    }
    *(float4*)(&opart[slice][d4]) = make_float4(ax, ay, az, aw);
  }
  __syncthreads();
  if (tid < 128) {
    float acc = 0.f;
#pragma unroll
    for (int i = 0; i < 8; ++i) acc += opart[i][tid];
    out[(size_t)b * 128 + tid] = acc;
  }
}

extern "C" void kernel_launch(void* const* d_in, const int* in_sizes, int n_in,
                              void* d_out, int out_size, void* d_ws, size_t ws_size,
                              hipStream_t stream) {
  const float* query = (const float*)d_in[0];
  const float* keys  = (const float*)d_in[1];
  const int*   maskp = (const int*)d_in[2];
  const float* W1    = (const float*)d_in[3];
  const float* b1    = (const float*)d_in[4];
  const float* a1    = (const float*)d_in[5];
  const float* W2    = (const float*)d_in[6];
  const float* b2    = (const float*)d_in[7];
  const float* a2    = (const float*)d_in[8];
  const float* W3    = (const float*)d_in[9];
  float* out = (float*)d_out;

  // workspace layout
  float* U        = (float*)d_ws;                        // 2 MiB
  short* Wk       = (short*)((char*)d_ws + 2097152);     // 64 KiB
  short* Wd       = Wk + 32768;                          // 64 KiB
  short* W2b      = Wd + 32768;                          // 64 KiB
  float* scores_g = (float*)((char*)d_ws + 2097152 + 196608);  // 1.6 MiB

  prep_weights<<<384, 256, 0, stream>>>(W1, W2, Wk, Wd, W2b);
  prep_u<<<256, 256, 0, stream>>>(query, W1, b1, U);
  din_scores<<<2048, 256, 0, stream>>>(query, keys, b2, a1, a2, W3,
                                       U, Wk, Wd, W2b, scores_g);
  din_wsum<<<2048, 256, 0, stream>>>(keys, maskp, scores_g, out);
}